// Round 7
// baseline (317.535 us; speedup 1.0000x reference)
//
#include <hip/hip_runtime.h>
#include <hip/hip_bf16.h>
#include <stdint.h>

#define BB 8
#define CC 512
#define KK 512
#define NN 4096

typedef __bf16 bf16x8 __attribute__((ext_vector_type(8)));
typedef float f32x4 __attribute__((ext_vector_type(4)));
typedef __attribute__((address_space(3))) uint8_t* lds_ptr_t;
typedef const __attribute__((address_space(1))) uint8_t* gbl_ptr_t;

static __device__ __forceinline__ unsigned short bf16_bits(float f) {
    __bf16 h = (__bf16)f;
    return __builtin_bit_cast(unsigned short, h);
}

// ---------------------------------------------------------------------------
// P1 (merged): z<8  -> y-branch: y fp32 -> yh, yl ([k][n]) + yT ([n][k])
//              z>=8 -> x-branch: x fp32 -> xh, xl (no transpose)
// 64x64 tile; y-branch transposes via padded LDS; yT stores vectorized ushort4.
// ---------------------------------------------------------------------------
__global__ void __launch_bounds__(256) prep(const float* __restrict__ x,
        const float* __restrict__ y,
        unsigned short* __restrict__ xh, unsigned short* __restrict__ xl,
        unsigned short* __restrict__ yh, unsigned short* __restrict__ yl,
        unsigned short* __restrict__ yT) {
    __shared__ unsigned short tile[64][66];
    const int n0 = blockIdx.x * 64, k0 = blockIdx.y * 64;
    const int t = threadIdx.x;
    if (blockIdx.z < 8) {
        const int b = blockIdx.z;
        const float* src = y + (size_t)b * KK * NN;
        unsigned short* dsth = yh + (size_t)b * KK * NN;
        unsigned short* dstl = yl + (size_t)b * KK * NN;
        unsigned short* dstT = yT + (size_t)b * NN * KK;
        #pragma unroll
        for (int i = 0; i < 4; ++i) {
            int idx = t + 256 * i;      // 0..1023 float4 units
            int r = idx >> 4;           // 0..63 (k)
            int c4 = (idx & 15) * 4;    // 0..60 (n)
            float4 v = *(const float4*)(src + (size_t)(k0 + r) * NN + n0 + c4);
            float a[4] = {v.x, v.y, v.z, v.w};
            unsigned short hb[4], lb[4];
            #pragma unroll
            for (int q = 0; q < 4; ++q) {
                __bf16 h = (__bf16)a[q];
                float hf = (float)h;
                __bf16 l = (__bf16)(a[q] - hf);
                hb[q] = __builtin_bit_cast(unsigned short, h);
                lb[q] = __builtin_bit_cast(unsigned short, l);
                tile[r][c4 + q] = hb[q];
            }
            size_t off = (size_t)(k0 + r) * NN + n0 + c4;
            *(ushort4*)(dsth + off) = make_ushort4(hb[0], hb[1], hb[2], hb[3]);
            *(ushort4*)(dstl + off) = make_ushort4(lb[0], lb[1], lb[2], lb[3]);
        }
        __syncthreads();
        #pragma unroll
        for (int i = 0; i < 4; ++i) {
            int idx = t + 256 * i;     // 0..1023 ushort4 units of yT tile
            int rn = idx >> 4;         // 0..63 (n)
            int ck = (idx & 15) * 4;   // 0..60 (k)
            *(ushort4*)(dstT + (size_t)(n0 + rn) * KK + k0 + ck) = make_ushort4(
                tile[ck + 0][rn], tile[ck + 1][rn], tile[ck + 2][rn], tile[ck + 3][rn]);
        }
    } else {
        const int b = blockIdx.z - 8;
        const float* src = x + (size_t)b * CC * NN;
        unsigned short* dsth = xh + (size_t)b * CC * NN;
        unsigned short* dstl = xl + (size_t)b * CC * NN;
        #pragma unroll
        for (int i = 0; i < 4; ++i) {
            int idx = t + 256 * i;
            int r = idx >> 4;           // 0..63 (c)
            int c4 = (idx & 15) * 4;    // 0..60 (n)
            float4 v = *(const float4*)(src + (size_t)(k0 + r) * NN + n0 + c4);
            float a[4] = {v.x, v.y, v.z, v.w};
            unsigned short hb[4], lb[4];
            #pragma unroll
            for (int q = 0; q < 4; ++q) {
                __bf16 h = (__bf16)a[q];
                float hf = (float)h;
                __bf16 l = (__bf16)(a[q] - hf);
                hb[q] = __builtin_bit_cast(unsigned short, h);
                lb[q] = __builtin_bit_cast(unsigned short, l);
            }
            size_t off = (size_t)(k0 + r) * NN + n0 + c4;
            *(ushort4*)(dsth + off) = make_ushort4(hb[0], hb[1], hb[2], hb[3]);
            *(ushort4*)(dstl + off) = make_ushort4(lb[0], lb[1], lb[2], lb[3]);
        }
    }
}

// ---------------------------------------------------------------------------
// K1: energy[b][c][k] = sum_n x[b][c][n]*y[b][k][n], split-bf16 (3 MFMAs).
// 128x128 output tile, BK=32 (LDS 32 KiB -> 4-5 blocks/CU resident; the
// occupancy was the R6 bottleneck at BK=64/64KiB/2 blocks). split-N=4,
// 32 K-steps of 32. Staging: global_load_lds w16, linear LDS dest +
// XOR-swizzled source; fragment ds_read_b128 uses the same involution
// c3 = u ^ ((r>>1)&3)  (64 B rows = 4 units; bank spread 2-way = free).
// ---------------------------------------------------------------------------
__global__ void __launch_bounds__(256) energy_gemm(
        const unsigned short* __restrict__ xh, const unsigned short* __restrict__ xl,
        const unsigned short* __restrict__ yh, const unsigned short* __restrict__ yl,
        float* __restrict__ epart) {
    __shared__ __align__(16) uint8_t smem[4 * 8192];  // Ah, Al, Bh, Bl : [128][32] bf16
    const int ktile = blockIdx.x;        // 0..3  (key tiles, 128 each)
    const int ctile = blockIdx.y;        // 0..3  (query tiles, 128 each)
    const int b = blockIdx.z >> 2;
    const int quarter = blockIdx.z & 3;  // split-N quarter (1024 contraction cols)
    const int t = threadIdx.x;
    const int wave = t >> 6, lane = t & 63;

    const size_t rowB = (size_t)NN * 2;  // 8192 B per bf16 row
    const uint8_t* srcBase[4];
    srcBase[0] = (const uint8_t*)xh + ((size_t)b * CC + ctile * 128) * rowB + (size_t)quarter * 2048;
    srcBase[1] = (const uint8_t*)xl + ((size_t)b * CC + ctile * 128) * rowB + (size_t)quarter * 2048;
    srcBase[2] = (const uint8_t*)yh + ((size_t)b * KK + ktile * 128) * rowB + (size_t)quarter * 2048;
    srcBase[3] = (const uint8_t*)yl + ((size_t)b * KK + ktile * 128) * rowB + (size_t)quarter * 2048;

    f32x4 acc[4][4] = {};
    const int waveRow = wave >> 1, waveCol = wave & 1;

    for (int step = 0; step < 32; ++step) {
        const size_t colByte = (size_t)step * 64;
        #pragma unroll
        for (int i = 0; i < 8; ++i) {
            const int tile = i >> 1;                // compile-time after unroll
            const int lc = (i & 1) * 4 + wave;      // chunk 0..7 within tile (1 KiB each)
            const int u = lc * 64 + lane;           // 16B unit index in tile 0..511
            const int r = u >> 2;                   // row 0..127
            const int c3 = (u & 3) ^ ((r >> 1) & 3);  // inverse-swizzled source unit
            const uint8_t* src = srcBase[tile] + (size_t)r * rowB + colByte + c3 * 16;
            __builtin_amdgcn_global_load_lds((gbl_ptr_t)src,
                (lds_ptr_t)(smem + tile * 8192 + lc * 1024), 16, 0, 0);
        }
        __syncthreads();
        {
            bf16x8 fah[4], fal[4], fbh[4], fbl[4];
            #pragma unroll
            for (int m = 0; m < 4; ++m) {
                int r = waveRow * 64 + m * 16 + (lane & 15);
                int c3 = (lane >> 4) ^ ((r >> 1) & 3);
                fah[m] = *(const bf16x8*)(smem + 0 * 8192 + r * 64 + c3 * 16);
                fal[m] = *(const bf16x8*)(smem + 1 * 8192 + r * 64 + c3 * 16);
            }
            #pragma unroll
            for (int n = 0; n < 4; ++n) {
                int r = waveCol * 64 + n * 16 + (lane & 15);
                int c3 = (lane >> 4) ^ ((r >> 1) & 3);
                fbh[n] = *(const bf16x8*)(smem + 2 * 8192 + r * 64 + c3 * 16);
                fbl[n] = *(const bf16x8*)(smem + 3 * 8192 + r * 64 + c3 * 16);
            }
            #pragma unroll
            for (int m = 0; m < 4; ++m)
            #pragma unroll
            for (int n = 0; n < 4; ++n) {
                acc[m][n] = __builtin_amdgcn_mfma_f32_16x16x32_bf16(fah[m], fbh[n], acc[m][n], 0, 0, 0);
                acc[m][n] = __builtin_amdgcn_mfma_f32_16x16x32_bf16(fah[m], fbl[n], acc[m][n], 0, 0, 0);
                acc[m][n] = __builtin_amdgcn_mfma_f32_16x16x32_bf16(fal[m], fbh[n], acc[m][n], 0, 0, 0);
            }
        }
        __syncthreads();
    }

    // C/D layout: col = lane&15, row = (lane>>4)*4 + reg  [m89-verified]
    float* eout = epart + (size_t)quarter * BB * CC * KK + (size_t)b * CC * KK;
    const int row0 = ctile * 128 + waveRow * 64;
    const int col0 = ktile * 128 + waveCol * 64;
    #pragma unroll
    for (int m = 0; m < 4; ++m)
    #pragma unroll
    for (int n = 0; n < 4; ++n)
    #pragma unroll
    for (int jj = 0; jj < 4; ++jj) {
        int rr = row0 + m * 16 + (lane >> 4) * 4 + jj;
        int cc2 = col0 + n * 16 + (lane & 15);
        eout[(size_t)rr * KK + cc2] = acc[m][n][jj];
    }
}

// ---------------------------------------------------------------------------
// K2: inverted softmax. softmax(max-e) == exp(min-e)/sum. One wave per row,
// vectorized f32x4 partial sums + ushort4 bf16 stores.
// ---------------------------------------------------------------------------
__global__ void __launch_bounds__(256) softmax_inv(
        const float* __restrict__ e, unsigned short* __restrict__ att) {
    const int t = threadIdx.x;
    const int wave = t >> 6, lane = t & 63;
    const int row = blockIdx.x * 4 + wave;   // 0..B*C-1
    const size_t Q4 = (size_t)BB * CC * KK / 4;   // quarter stride in float4s
    const f32x4* p = (const f32x4*)(e) + (size_t)row * (KK / 4);
    f32x4 v[2];
    float mn = 3.0e38f;
    #pragma unroll
    for (int i = 0; i < 2; ++i) {
        int c = lane + i * 64;               // 0..127 float4 units of the row
        v[i] = p[c] + p[Q4 + c] + p[2 * Q4 + c] + p[3 * Q4 + c];
        #pragma unroll
        for (int q = 0; q < 4; ++q) mn = fminf(mn, v[i][q]);
    }
    #pragma unroll
    for (int off = 32; off > 0; off >>= 1) mn = fminf(mn, __shfl_xor(mn, off));
    float s = 0.f;
    f32x4 pr[2];
    #pragma unroll
    for (int i = 0; i < 2; ++i)
    #pragma unroll
    for (int q = 0; q < 4; ++q) { pr[i][q] = __expf(mn - v[i][q]); s += pr[i][q]; }
    #pragma unroll
    for (int off = 32; off > 0; off >>= 1) s += __shfl_xor(s, off);
    float inv = 1.0f / s;
    ushort4* arow = (ushort4*)(att + (size_t)row * KK);
    #pragma unroll
    for (int i = 0; i < 2; ++i) {
        arow[lane + i * 64] = make_ushort4(
            bf16_bits(pr[i][0] * inv), bf16_bits(pr[i][1] * inv),
            bf16_bits(pr[i][2] * inv), bf16_bits(pr[i][3] * inv));
    }
}

// ---------------------------------------------------------------------------
// K3: out[b][c][n] = x[b][c][n] + scale * sum_k att[b][c][k]*yT[b][n][k].
// 128x128 tile, BK=64, 8 k-steps; swizzled global_load_lds staging.
// 1D grid 1024, XCD = batch b -> yT/att b-slice L2-resident.
// ---------------------------------------------------------------------------
__global__ void __launch_bounds__(256) pv_residual(
        const unsigned short* __restrict__ att, const unsigned short* __restrict__ yT,
        const float* __restrict__ x, const float* __restrict__ scale,
        float* __restrict__ out) {
    __shared__ __align__(16) uint8_t smem[2 * 16384];   // A: att [128][64], B: yT [128][64]
    const int j = blockIdx.x;
    const int b = j & 7;                 // XCD = batch
    const int rem2 = j >> 3;             // 0..127
    const int ntile = rem2 & 31;         // 0..31
    const int ctile = rem2 >> 5;         // 0..3
    const int t = threadIdx.x;
    const int wave = t >> 6, lane = t & 63;
    const size_t rowB = (size_t)KK * 2;   // 1024 B
    const uint8_t* srcA = (const uint8_t*)att + ((size_t)b * CC + ctile * 128) * rowB;
    const uint8_t* srcB = (const uint8_t*)yT  + ((size_t)b * NN + ntile * 128) * rowB;

    f32x4 acc[4][4] = {};
    const int waveRow = wave >> 1, waveCol = wave & 1;

    for (int step = 0; step < 8; ++step) {
        const size_t colByte = (size_t)step * 128;
        #pragma unroll
        for (int i = 0; i < 8; ++i) {
            const uint8_t* base = (i < 4) ? srcA : srcB;  // compile-time per unrolled i
            const int tile = i >> 2;
            const int lc = (i & 3) * 4 + wave;            // 0..15
            const int u = lc * 64 + lane;
            const int r = u >> 3;                         // 0..127
            const int c3 = (u & 7) ^ (r & 7);
            const uint8_t* src = base + (size_t)r * rowB + colByte + c3 * 16;
            __builtin_amdgcn_global_load_lds((gbl_ptr_t)src,
                (lds_ptr_t)(smem + tile * 16384 + lc * 1024), 16, 0, 0);
        }
        __syncthreads();
        #pragma unroll
        for (int kf = 0; kf < 2; ++kf) {
            bf16x8 fa[4], fb[4];
            #pragma unroll
            for (int m = 0; m < 4; ++m) {
                int r = waveRow * 64 + m * 16 + (lane & 15);
                int c3 = (kf * 4 + (lane >> 4)) ^ (r & 7);
                fa[m] = *(const bf16x8*)(smem + r * 128 + c3 * 16);
            }
            #pragma unroll
            for (int n = 0; n < 4; ++n) {
                int r = waveCol * 64 + n * 16 + (lane & 15);
                int c3 = (kf * 4 + (lane >> 4)) ^ (r & 7);
                fb[n] = *(const bf16x8*)(smem + 16384 + r * 128 + c3 * 16);
            }
            #pragma unroll
            for (int m = 0; m < 4; ++m)
            #pragma unroll
            for (int n = 0; n < 4; ++n)
                acc[m][n] = __builtin_amdgcn_mfma_f32_16x16x32_bf16(fa[m], fb[n], acc[m][n], 0, 0, 0);
        }
        __syncthreads();
    }

    const float s = scale[0];
    const int row0 = ctile * 128 + waveRow * 64;
    const int col0 = ntile * 128 + waveCol * 64;
    #pragma unroll
    for (int m = 0; m < 4; ++m)
    #pragma unroll
    for (int n = 0; n < 4; ++n)
    #pragma unroll
    for (int jj = 0; jj < 4; ++jj) {
        int rr = row0 + m * 16 + (lane >> 4) * 4 + jj;
        int cc2 = col0 + n * 16 + (lane & 15);
        size_t idx = ((size_t)b * CC + rr) * NN + cc2;
        out[idx] = x[idx] + s * acc[m][n][jj];
    }
}

// ---------------------------------------------------------------------------
// Buffer plan (ws 132 MiB; d_out doubles as scratch):
//   ws[0,32M)    xh
//   ws[32M,64M)  yh
//   ws[64M,96M)  yl
//   ws[96M,128M) yT
//   ws[128M,132M) att
//   d_out[0,32M)  4 x 8 MiB energy partials  (dead after softmax_inv)
//   d_out[32M,64M) xl                        (dead after energy_gemm)
//   pv_residual finally overwrites all of d_out.
// ---------------------------------------------------------------------------
extern "C" void kernel_launch(void* const* d_in, const int* in_sizes, int n_in,
                              void* d_out, int out_size, void* d_ws, size_t ws_size,
                              hipStream_t stream) {
    const float* x = (const float*)d_in[0];
    const float* y = (const float*)d_in[1];
    const float* scale = (const float*)d_in[2];
    float* out = (float*)d_out;
    uint8_t* ws = (uint8_t*)d_ws;
    uint8_t* ob = (uint8_t*)d_out;
    const size_t MB = 1024 * 1024;
    unsigned short* xh = (unsigned short*)(ws + 0 * MB);
    unsigned short* yh = (unsigned short*)(ws + 32 * MB);
    unsigned short* yl = (unsigned short*)(ws + 64 * MB);
    unsigned short* yT = (unsigned short*)(ws + 96 * MB);
    unsigned short* att = (unsigned short*)(ws + 128 * MB);
    float* epart = (float*)(ob + 0 * MB);                  // d_out lower half
    unsigned short* xl = (unsigned short*)(ob + 32 * MB);  // d_out upper half

    prep<<<dim3(NN / 64, KK / 64, 16), 256, 0, stream>>>(x, y, xh, xl, yh, yl, yT);
    energy_gemm<<<dim3(4, 4, BB * 4), 256, 0, stream>>>(xh, xl, yh, yl, epart);
    softmax_inv<<<BB * CC / 4, 256, 0, stream>>>(epart, att);
    pv_residual<<<1024, 256, 0, stream>>>(att, yT, x, scale, out);
}

// Round 8
// 317.026 us; speedup vs baseline: 1.0016x; 1.0016x over previous
//
#include <hip/hip_runtime.h>
#include <hip/hip_bf16.h>
#include <stdint.h>

#define BB 8
#define CC 512
#define KK 512
#define NN 4096

typedef __bf16 bf16x8 __attribute__((ext_vector_type(8)));
typedef float f32x4 __attribute__((ext_vector_type(4)));
typedef __attribute__((address_space(3))) uint8_t* lds_ptr_t;
typedef const __attribute__((address_space(1))) uint8_t* gbl_ptr_t;

static __device__ __forceinline__ unsigned short bf16_bits(float f) {
    __bf16 h = (__bf16)f;
    return __builtin_bit_cast(unsigned short, h);
}

// ---------------------------------------------------------------------------
// P1 (merged): z<8  -> y-branch: y fp32 -> yh, yl ([k][n]) + yT ([n][k])
//              z>=8 -> x-branch: x fp32 -> xh, xl (no transpose)
// 64x64 tile; y-branch transposes via padded LDS; yT stores vectorized ushort4.
// ---------------------------------------------------------------------------
__global__ void __launch_bounds__(256) prep(const float* __restrict__ x,
        const float* __restrict__ y,
        unsigned short* __restrict__ xh, unsigned short* __restrict__ xl,
        unsigned short* __restrict__ yh, unsigned short* __restrict__ yl,
        unsigned short* __restrict__ yT) {
    __shared__ unsigned short tile[64][66];
    const int n0 = blockIdx.x * 64, k0 = blockIdx.y * 64;
    const int t = threadIdx.x;
    if (blockIdx.z < 8) {
        const int b = blockIdx.z;
        const float* src = y + (size_t)b * KK * NN;
        unsigned short* dsth = yh + (size_t)b * KK * NN;
        unsigned short* dstl = yl + (size_t)b * KK * NN;
        unsigned short* dstT = yT + (size_t)b * NN * KK;
        #pragma unroll
        for (int i = 0; i < 4; ++i) {
            int idx = t + 256 * i;      // 0..1023 float4 units
            int r = idx >> 4;           // 0..63 (k)
            int c4 = (idx & 15) * 4;    // 0..60 (n)
            float4 v = *(const float4*)(src + (size_t)(k0 + r) * NN + n0 + c4);
            float a[4] = {v.x, v.y, v.z, v.w};
            unsigned short hb[4], lb[4];
            #pragma unroll
            for (int q = 0; q < 4; ++q) {
                __bf16 h = (__bf16)a[q];
                float hf = (float)h;
                __bf16 l = (__bf16)(a[q] - hf);
                hb[q] = __builtin_bit_cast(unsigned short, h);
                lb[q] = __builtin_bit_cast(unsigned short, l);
                tile[r][c4 + q] = hb[q];
            }
            size_t off = (size_t)(k0 + r) * NN + n0 + c4;
            *(ushort4*)(dsth + off) = make_ushort4(hb[0], hb[1], hb[2], hb[3]);
            *(ushort4*)(dstl + off) = make_ushort4(lb[0], lb[1], lb[2], lb[3]);
        }
        __syncthreads();
        #pragma unroll
        for (int i = 0; i < 4; ++i) {
            int idx = t + 256 * i;     // 0..1023 ushort4 units of yT tile
            int rn = idx >> 4;         // 0..63 (n)
            int ck = (idx & 15) * 4;   // 0..60 (k)
            *(ushort4*)(dstT + (size_t)(n0 + rn) * KK + k0 + ck) = make_ushort4(
                tile[ck + 0][rn], tile[ck + 1][rn], tile[ck + 2][rn], tile[ck + 3][rn]);
        }
    } else {
        const int b = blockIdx.z - 8;
        const float* src = x + (size_t)b * CC * NN;
        unsigned short* dsth = xh + (size_t)b * CC * NN;
        unsigned short* dstl = xl + (size_t)b * CC * NN;
        #pragma unroll
        for (int i = 0; i < 4; ++i) {
            int idx = t + 256 * i;
            int r = idx >> 4;           // 0..63 (c)
            int c4 = (idx & 15) * 4;    // 0..60 (n)
            float4 v = *(const float4*)(src + (size_t)(k0 + r) * NN + n0 + c4);
            float a[4] = {v.x, v.y, v.z, v.w};
            unsigned short hb[4], lb[4];
            #pragma unroll
            for (int q = 0; q < 4; ++q) {
                __bf16 h = (__bf16)a[q];
                float hf = (float)h;
                __bf16 l = (__bf16)(a[q] - hf);
                hb[q] = __builtin_bit_cast(unsigned short, h);
                lb[q] = __builtin_bit_cast(unsigned short, l);
            }
            size_t off = (size_t)(k0 + r) * NN + n0 + c4;
            *(ushort4*)(dsth + off) = make_ushort4(hb[0], hb[1], hb[2], hb[3]);
            *(ushort4*)(dstl + off) = make_ushort4(lb[0], lb[1], lb[2], lb[3]);
        }
    }
}

// ---------------------------------------------------------------------------
// K1: energy[b][c][k] = sum_n x[b][c][n]*y[b][k][n], split-bf16 (3 MFMAs,
// all accumulating into ONE acc chain per (m,n)).
// Tile 128x64, BK=64, 512 threads = 8 waves (4 row-bands x 2 col-halves),
// wave-tile 32x32. LDS 48 KiB -> 3 blocks/CU; __launch_bounds__(512,6)
// -> 24 waves/CU (the R6/R7 kernels were stuck at ~19% occupancy: grid or
// fetch-granularity limited). 128-B rows keep HBM fetch efficient (the R7
// 64-B-row variant over-fetched 1.65x). split-N=4, 16 K-steps.
// Staging: global_load_lds w16, linear LDS dest + XOR-swizzled source
// (c3 = u ^ (r&7)); same involution on the ds_read_b128 side. Proven
// conflict-free (R3/R6: SQ_LDS_BANK_CONFLICT = 0).
// ---------------------------------------------------------------------------
__global__ void __launch_bounds__(512, 6) energy_gemm(
        const unsigned short* __restrict__ xh, const unsigned short* __restrict__ xl,
        const unsigned short* __restrict__ yh, const unsigned short* __restrict__ yl,
        float* __restrict__ epart) {
    // Ah[128][64]bf16 @0 (16K), Al @16384, Bh[64][64] @32768 (8K), Bl @40960
    __shared__ __align__(16) uint8_t smem[49152];
    const int ktile = blockIdx.x;        // 0..7  (key tiles, 64 each)
    const int ctile = blockIdx.y;        // 0..3  (query tiles, 128 each)
    const int b = blockIdx.z >> 2;
    const int quarter = blockIdx.z & 3;  // split-N quarter (1024 contraction cols)
    const int t = threadIdx.x;
    const int wave = t >> 6, lane = t & 63;

    const size_t rowB = (size_t)NN * 2;  // 8192 B per bf16 row
    const uint8_t* srcBase[4];
    srcBase[0] = (const uint8_t*)xh + ((size_t)b * CC + ctile * 128) * rowB + (size_t)quarter * 2048;
    srcBase[1] = (const uint8_t*)xl + ((size_t)b * CC + ctile * 128) * rowB + (size_t)quarter * 2048;
    srcBase[2] = (const uint8_t*)yh + ((size_t)b * KK + ktile * 64) * rowB + (size_t)quarter * 2048;
    srcBase[3] = (const uint8_t*)yl + ((size_t)b * KK + ktile * 64) * rowB + (size_t)quarter * 2048;
    const int tileOff[4] = {0, 16384, 32768, 40960};

    f32x4 acc[2][2] = {};
    const int waveRow = wave >> 1;       // 0..3 (32-row band)
    const int waveCol = wave & 1;        // 0..1 (32-col half)

    for (int step = 0; step < 16; ++step) {
        const size_t colByte = (size_t)step * 128;
        // 48 chunks of 1 KiB: Ah 16, Al 16, Bh 8, Bl 8; 8 waves x 6 issues.
        #pragma unroll
        for (int i = 0; i < 6; ++i) {
            // chunk c = i*8 + wave; tile & lc compile-time per i:
            const int tile = (i < 2) ? 0 : (i < 4) ? 1 : (i == 4) ? 2 : 3;
            const int lc = (i < 4) ? ((i & 1) * 8 + wave) : wave;
            const int u = lc * 64 + lane;       // 16B unit index in tile
            const int r = u >> 3;               // row (A: 0..127, B: 0..63)
            const int c3 = (u & 7) ^ (r & 7);   // inverse-swizzled source unit
            const uint8_t* src = srcBase[tile] + (size_t)r * rowB + colByte + c3 * 16;
            __builtin_amdgcn_global_load_lds((gbl_ptr_t)src,
                (lds_ptr_t)(smem + tileOff[tile] + lc * 1024), 16, 0, 0);
        }
        __syncthreads();
        #pragma unroll
        for (int kf = 0; kf < 2; ++kf) {
            bf16x8 fah[2], fal[2], fbh[2], fbl[2];
            #pragma unroll
            for (int m = 0; m < 2; ++m) {
                int r = waveRow * 32 + m * 16 + (lane & 15);
                int c3 = (kf * 4 + (lane >> 4)) ^ (r & 7);
                fah[m] = *(const bf16x8*)(smem + r * 128 + c3 * 16);
                fal[m] = *(const bf16x8*)(smem + 16384 + r * 128 + c3 * 16);
            }
            #pragma unroll
            for (int n = 0; n < 2; ++n) {
                int r = waveCol * 32 + n * 16 + (lane & 15);
                int c3 = (kf * 4 + (lane >> 4)) ^ (r & 7);
                fbh[n] = *(const bf16x8*)(smem + 32768 + r * 128 + c3 * 16);
                fbl[n] = *(const bf16x8*)(smem + 40960 + r * 128 + c3 * 16);
            }
            #pragma unroll
            for (int m = 0; m < 2; ++m)
            #pragma unroll
            for (int n = 0; n < 2; ++n) {
                acc[m][n] = __builtin_amdgcn_mfma_f32_16x16x32_bf16(fah[m], fbh[n], acc[m][n], 0, 0, 0);
                acc[m][n] = __builtin_amdgcn_mfma_f32_16x16x32_bf16(fah[m], fbl[n], acc[m][n], 0, 0, 0);
                acc[m][n] = __builtin_amdgcn_mfma_f32_16x16x32_bf16(fal[m], fbh[n], acc[m][n], 0, 0, 0);
            }
        }
        __syncthreads();
    }

    // C/D layout: col = lane&15, row = (lane>>4)*4 + reg  [m89-verified]
    float* eout = epart + (size_t)quarter * BB * CC * KK + (size_t)b * CC * KK;
    const int row0 = ctile * 128 + waveRow * 32;
    const int col0 = ktile * 64 + waveCol * 32;
    #pragma unroll
    for (int m = 0; m < 2; ++m)
    #pragma unroll
    for (int n = 0; n < 2; ++n)
    #pragma unroll
    for (int jj = 0; jj < 4; ++jj) {
        int rr = row0 + m * 16 + (lane >> 4) * 4 + jj;
        int cc2 = col0 + n * 16 + (lane & 15);
        eout[(size_t)rr * KK + cc2] = acc[m][n][jj];
    }
}

// ---------------------------------------------------------------------------
// K2: inverted softmax. softmax(max-e) == exp(min-e)/sum. One wave per row,
// vectorized f32x4 partial sums + ushort4 bf16 stores.
// ---------------------------------------------------------------------------
__global__ void __launch_bounds__(256) softmax_inv(
        const float* __restrict__ e, unsigned short* __restrict__ att) {
    const int t = threadIdx.x;
    const int wave = t >> 6, lane = t & 63;
    const int row = blockIdx.x * 4 + wave;   // 0..B*C-1
    const size_t Q4 = (size_t)BB * CC * KK / 4;   // quarter stride in float4s
    const f32x4* p = (const f32x4*)(e) + (size_t)row * (KK / 4);
    f32x4 v[2];
    float mn = 3.0e38f;
    #pragma unroll
    for (int i = 0; i < 2; ++i) {
        int c = lane + i * 64;               // 0..127 float4 units of the row
        v[i] = p[c] + p[Q4 + c] + p[2 * Q4 + c] + p[3 * Q4 + c];
        #pragma unroll
        for (int q = 0; q < 4; ++q) mn = fminf(mn, v[i][q]);
    }
    #pragma unroll
    for (int off = 32; off > 0; off >>= 1) mn = fminf(mn, __shfl_xor(mn, off));
    float s = 0.f;
    f32x4 pr[2];
    #pragma unroll
    for (int i = 0; i < 2; ++i)
    #pragma unroll
    for (int q = 0; q < 4; ++q) { pr[i][q] = __expf(mn - v[i][q]); s += pr[i][q]; }
    #pragma unroll
    for (int off = 32; off > 0; off >>= 1) s += __shfl_xor(s, off);
    float inv = 1.0f / s;
    ushort4* arow = (ushort4*)(att + (size_t)row * KK);
    #pragma unroll
    for (int i = 0; i < 2; ++i) {
        arow[lane + i * 64] = make_ushort4(
            bf16_bits(pr[i][0] * inv), bf16_bits(pr[i][1] * inv),
            bf16_bits(pr[i][2] * inv), bf16_bits(pr[i][3] * inv));
    }
}

// ---------------------------------------------------------------------------
// K3: out[b][c][n] = x[b][c][n] + scale * sum_k att[b][c][k]*yT[b][n][k].
// 128x128 tile, BK=64, 8 k-steps; swizzled global_load_lds staging.
// 1D grid 1024, XCD = batch b -> yT/att b-slice L2-resident.
// ---------------------------------------------------------------------------
__global__ void __launch_bounds__(256) pv_residual(
        const unsigned short* __restrict__ att, const unsigned short* __restrict__ yT,
        const float* __restrict__ x, const float* __restrict__ scale,
        float* __restrict__ out) {
    __shared__ __align__(16) uint8_t smem[2 * 16384];   // A: att [128][64], B: yT [128][64]
    const int j = blockIdx.x;
    const int b = j & 7;                 // XCD = batch
    const int rem2 = j >> 3;             // 0..127
    const int ntile = rem2 & 31;         // 0..31
    const int ctile = rem2 >> 5;         // 0..3
    const int t = threadIdx.x;
    const int wave = t >> 6, lane = t & 63;
    const size_t rowB = (size_t)KK * 2;   // 1024 B
    const uint8_t* srcA = (const uint8_t*)att + ((size_t)b * CC + ctile * 128) * rowB;
    const uint8_t* srcB = (const uint8_t*)yT  + ((size_t)b * NN + ntile * 128) * rowB;

    f32x4 acc[4][4] = {};
    const int waveRow = wave >> 1, waveCol = wave & 1;

    for (int step = 0; step < 8; ++step) {
        const size_t colByte = (size_t)step * 128;
        #pragma unroll
        for (int i = 0; i < 8; ++i) {
            const uint8_t* base = (i < 4) ? srcA : srcB;  // compile-time per unrolled i
            const int tile = i >> 2;
            const int lc = (i & 3) * 4 + wave;            // 0..15
            const int u = lc * 64 + lane;
            const int r = u >> 3;                         // 0..127
            const int c3 = (u & 7) ^ (r & 7);
            const uint8_t* src = base + (size_t)r * rowB + colByte + c3 * 16;
            __builtin_amdgcn_global_load_lds((gbl_ptr_t)src,
                (lds_ptr_t)(smem + tile * 16384 + lc * 1024), 16, 0, 0);
        }
        __syncthreads();
        #pragma unroll
        for (int kf = 0; kf < 2; ++kf) {
            bf16x8 fa[4], fb[4];
            #pragma unroll
            for (int m = 0; m < 4; ++m) {
                int r = waveRow * 64 + m * 16 + (lane & 15);
                int c3 = (kf * 4 + (lane >> 4)) ^ (r & 7);
                fa[m] = *(const bf16x8*)(smem + r * 128 + c3 * 16);
            }
            #pragma unroll
            for (int n = 0; n < 4; ++n) {
                int r = waveCol * 64 + n * 16 + (lane & 15);
                int c3 = (kf * 4 + (lane >> 4)) ^ (r & 7);
                fb[n] = *(const bf16x8*)(smem + 16384 + r * 128 + c3 * 16);
            }
            #pragma unroll
            for (int m = 0; m < 4; ++m)
            #pragma unroll
            for (int n = 0; n < 4; ++n)
                acc[m][n] = __builtin_amdgcn_mfma_f32_16x16x32_bf16(fa[m], fb[n], acc[m][n], 0, 0, 0);
        }
        __syncthreads();
    }

    const float s = scale[0];
    const int row0 = ctile * 128 + waveRow * 64;
    const int col0 = ntile * 128 + waveCol * 64;
    #pragma unroll
    for (int m = 0; m < 4; ++m)
    #pragma unroll
    for (int n = 0; n < 4; ++n)
    #pragma unroll
    for (int jj = 0; jj < 4; ++jj) {
        int rr = row0 + m * 16 + (lane >> 4) * 4 + jj;
        int cc2 = col0 + n * 16 + (lane & 15);
        size_t idx = ((size_t)b * CC + rr) * NN + cc2;
        out[idx] = x[idx] + s * acc[m][n][jj];
    }
}

// ---------------------------------------------------------------------------
// Buffer plan (ws 132 MiB; d_out doubles as scratch):
//   ws[0,32M)    xh
//   ws[32M,64M)  yh
//   ws[64M,96M)  yl
//   ws[96M,128M) yT
//   ws[128M,132M) att
//   d_out[0,32M)  4 x 8 MiB energy partials  (dead after softmax_inv)
//   d_out[32M,64M) xl                        (dead after energy_gemm)
//   pv_residual finally overwrites all of d_out.
// ---------------------------------------------------------------------------
extern "C" void kernel_launch(void* const* d_in, const int* in_sizes, int n_in,
                              void* d_out, int out_size, void* d_ws, size_t ws_size,
                              hipStream_t stream) {
    const float* x = (const float*)d_in[0];
    const float* y = (const float*)d_in[1];
    const float* scale = (const float*)d_in[2];
    float* out = (float*)d_out;
    uint8_t* ws = (uint8_t*)d_ws;
    uint8_t* ob = (uint8_t*)d_out;
    const size_t MB = 1024 * 1024;
    unsigned short* xh = (unsigned short*)(ws + 0 * MB);
    unsigned short* yh = (unsigned short*)(ws + 32 * MB);
    unsigned short* yl = (unsigned short*)(ws + 64 * MB);
    unsigned short* yT = (unsigned short*)(ws + 96 * MB);
    unsigned short* att = (unsigned short*)(ws + 128 * MB);
    float* epart = (float*)(ob + 0 * MB);                  // d_out lower half
    unsigned short* xl = (unsigned short*)(ob + 32 * MB);  // d_out upper half

    prep<<<dim3(NN / 64, KK / 64, 16), 256, 0, stream>>>(x, y, xh, xl, yh, yl, yT);
    energy_gemm<<<dim3(8, 4, BB * 4), 512, 0, stream>>>(xh, xl, yh, yl, epart);
    softmax_inv<<<BB * CC / 4, 256, 0, stream>>>(epart, att);
    pv_residual<<<1024, 256, 0, stream>>>(att, yT, x, scale, out);
}